// Round 8
// baseline (767.794 us; speedup 1.0000x reference)
//
#include <hip/hip_runtime.h>
#include <cstdint>

constexpr int B    = 256;
constexpr int S    = 33;
constexpr int D    = 42;
constexpr int H    = 128;
constexpr int HFF  = 256;
constexpr int T    = 20;
constexpr int NSTEP = S - 1;   // 32
constexpr int DP   = D / 2;    // 21 f16 d-pairs
constexpr int ADW  = 8192;     // dwords per (s,b) A-slice (e5m2, 32 KB)
constexpr int CH   = 16;       // steps per chunk (A chunk = 128 MiB)
#define BN_SCALE 0.9999950000374997f

typedef _Float16 h2v __attribute__((ext_vector_type(2)));
union UH2 { uint32_t u; h2v h; };

__device__ __forceinline__ float fdot2u(uint32_t a, uint32_t b, float c) {
    UH2 x, y; x.u = a; y.u = b;
    return __builtin_amdgcn_fdot2(x.h, y.h, c, false);
}
__device__ __forceinline__ uint32_t packh2(float a, float b) {
    UH2 u; u.h = h2v{(_Float16)a, (_Float16)b}; return u.u;
}
__device__ __forceinline__ float gelu_exact(float x) {
    return 0.5f * x * (1.0f + erff(x * 0.70710678118654752f));
}
// fast gelu for the hot scan (err ~3e-4, far under the 1e-2 threshold)
__device__ __forceinline__ float gelu_fast(float x) {
    float inner = x * (1.0f + 0.044715f * x * x);
    float E = __expf(1.5957691216f * inner);
    return x * E * __frcp_rn(E + 1.0f);
}

// ---------------------------------------------------------------------------
// Pack (one-time):
//  wcolQ[r*1024 + t]: quarter-K weight slices for the 1024-thread scan.
//    t -> (j = t>>2, q = t&3).
//    r<16:        L0, ip = q*16 + r        pair (w0[2ip][j], w0[2ip+1][j])
//    r in [16,48): L1, ip = q*32 + (r-16)  from w1
//    r in [48,80): L2, ip = q*32 + (r-48)  from w2
//  wq[u*84 + row*21 + dp], u = k*128+h (k = e-quad): row e = 4k+row of w3.
// ---------------------------------------------------------------------------
__global__ void pack_kernel(const float* __restrict__ w0, const float* __restrict__ w1,
                            const float* __restrict__ w2, const float* __restrict__ w3,
                            uint32_t* __restrict__ wcolQ, uint32_t* __restrict__ wq) {
    int idx = blockIdx.x * 256 + threadIdx.x;
    if (idx < 80 * 1024) {
        int r = idx >> 10, t = idx & 1023;
        int j = t >> 2, q = t & 3;
        float a, bb;
        if (r < 16)      { int ip = q * 16 + r;        a = w0[(2*ip)*HFF + j]; bb = w0[(2*ip+1)*HFF + j]; }
        else if (r < 48) { int ip = q * 32 + (r - 16); a = w1[(2*ip)*HFF + j]; bb = w1[(2*ip+1)*HFF + j]; }
        else             { int ip = q * 32 + (r - 48); a = w2[(2*ip)*HFF + j]; bb = w2[(2*ip+1)*HFF + j]; }
        wcolQ[idx] = packh2(a, bb);
    }
    if (idx < 8192 * 84) {
        int u = idx / 84, r = idx % 84;
        int k = u >> 7, h = u & 127;
        int row = r / 21, dp = r % 21;
        int e = 4 * k + row;
        wq[idx] = packh2(w3[e * (H * D) + h * D + 2 * dp],
                         w3[e * (H * D) + h * D + 2 * dp + 1]);
    }
}

// ---------------------------------------------------------------------------
// Prep: encoder z0, dxdt f16 pairs, bd3g[s,b,h], dt.  1 block/sample.
// ---------------------------------------------------------------------------
__global__ void prep_kernel(const float* __restrict__ path, const float* __restrict__ ts,
                            const float* __restrict__ ew1, const float* __restrict__ eb1,
                            const float* __restrict__ eg1, const float* __restrict__ ebe1,
                            const float* __restrict__ ew2, const float* __restrict__ eb2,
                            const float* __restrict__ eg2, const float* __restrict__ ebe2,
                            const float* __restrict__ b3,
                            float* __restrict__ zbuf, uint32_t* __restrict__ dxdtp,
                            float* __restrict__ bd3g, float* __restrict__ dtb) {
    __shared__ float x0[D], hb[H], dxs[NSTEP][D];
    int b = blockIdx.x, tid = threadIdx.x;
    if (tid < D) x0[tid] = path[b * S * D + tid];
    __syncthreads();
    {
        float acc = eb1[tid];
        for (int d = 0; d < D; ++d) acc += x0[d] * ew1[d * H + tid];
        hb[tid] = gelu_exact(acc * (eg1[tid] * BN_SCALE) + ebe1[tid]);
    }
    __syncthreads();
    {
        float acc = eb2[tid];
        for (int i = 0; i < H; ++i) acc += hb[i] * ew2[i * H + tid];
        zbuf[b * H + tid] = acc * (eg2[tid] * BN_SCALE) + ebe2[tid];
    }
    for (int idx = tid; idx < NSTEP * DP; idx += 128) {
        int s = idx / DP, jj = idx % DP;
        float dtv = ts[s + 1] - ts[s];
        int base = b * S * D + s * D + 2 * jj;
        float v0 = (path[base + D] - path[base]) / dtv;
        float v1 = (path[base + D + 1] - path[base + 1]) / dtv;
        dxs[s][2 * jj] = v0; dxs[s][2 * jj + 1] = v1;
        dxdtp[(s * B + b) * DP + jj] = packh2(v0, v1);
    }
    __syncthreads();
    for (int s = 0; s < NSTEP; ++s) {
        float a = 0.f;
        for (int d = 0; d < D; ++d) a += b3[tid * D + d] * dxs[s][d];
        bd3g[(size_t)(s * B + b) * H + tid] = a;
    }
    if (b == 0 && tid < NSTEP) dtb[tid] = ts[tid + 1] - ts[tid];
}

// ---------------------------------------------------------------------------
// A-phase (per 16-step chunk).  launch_bounds(256,1): wr[84] stays in VGPRs
// (R6/R7 ran at VGPR=48 -> scratch spill; this was the hidden cost).
// ---------------------------------------------------------------------------
__global__ void __launch_bounds__(256, 1) aphase_kernel(
    const uint32_t* __restrict__ wq, const uint32_t* __restrict__ dxdtp,
    uint32_t* __restrict__ Ach, int s0) {
    __shared__ uint32_t dxs[64][DP];                   // 5.25 KB
    int t = threadIdx.x;
    int ub = blockIdx.x & 31, sbc = blockIdx.x >> 5;
    int u = ub * 256 + t;
    uint32_t wr[84];
    const uint32_t* wp = wq + (size_t)u * 84;
#pragma unroll
    for (int r = 0; r < 84; ++r) wr[r] = wp[r];
    for (int idx = t; idx < 64 * DP; idx += 256) {
        int i = idx / DP, j2 = idx % DP;
        int sbl = sbc * 64 + i;
        int s = s0 + (sbl >> 8), b = sbl & 255;
        dxs[i][j2] = dxdtp[(size_t)(s * B + b) * DP + j2];
    }
    __syncthreads();
    for (int i = 0; i < 64; ++i) {
        int sbl = sbc * 64 + i;
        float a0 = 0.f, a1 = 0.f, a2 = 0.f, a3 = 0.f;
#pragma unroll
        for (int j = 0; j < 21; ++j) {
            uint32_t dx = dxs[i][j];
            a0 = fdot2u(wr[j],      dx, a0);
            a1 = fdot2u(wr[21 + j], dx, a1);
            a2 = fdot2u(wr[42 + j], dx, a2);
            a3 = fdot2u(wr[63 + j], dx, a3);
        }
        uint32_t P01 = packh2(a0, a1) + 0x00800080u;
        uint32_t P23 = packh2(a2, a3) + 0x00800080u;
        uint32_t Q = __builtin_amdgcn_perm(P23, P01, 0x07050301u);
        Ach[(size_t)sbl * ADW + u] = Q;
    }
}

// ---------------------------------------------------------------------------
// Scan: persistent, 1 block = 1 sample, 1024 threads (16 waves/CU).
// Quarter-K per lane -> only 80 weight dwords/thread: register-resident under
// the 128-VGPR cap a 1024-thread block imposes.  Combine via 2x shfl_xor.
// y-buffers use quarter stride 36 dwords -> conflict-free quad reads.
// ---------------------------------------------------------------------------
__global__ void __launch_bounds__(1024) scan_kernel(
    const uint32_t* __restrict__ wcolQ, const uint32_t* __restrict__ Ach,
    const float* __restrict__ vb0, const float* __restrict__ vg0, const float* __restrict__ vbe0,
    const float* __restrict__ vb1, const float* __restrict__ vg1, const float* __restrict__ vbe1,
    const float* __restrict__ vb2, const float* __restrict__ vg2, const float* __restrict__ vbe2,
    const float* __restrict__ bd3g, const float* __restrict__ dtb,
    float* __restrict__ zbuf, int s0) {
    __shared__ uint32_t ABUF[2][ADW];                 // 64 KB
    __shared__ uint32_t zzPd[64];                     // 128 f16
    __shared__ uint32_t yA[144], yB[144], yC[144];    // quarter stride 36
    __shared__ float psum[8][128];
    int t = threadIdx.x, b = blockIdx.x;
    int j = t >> 2, q = t & 3;                        // MLP role
    int h = t & 127, g = t >> 7;                      // L3/state role
    uint32_t w0h[16], w1h[32], w2h[32];
#pragma unroll
    for (int r = 0; r < 16; ++r) w0h[r] = wcolQ[r * 1024 + t];
#pragma unroll
    for (int r = 0; r < 32; ++r) w1h[r] = wcolQ[(16 + r) * 1024 + t];
#pragma unroll
    for (int r = 0; r < 32; ++r) w2h[r] = wcolQ[(48 + r) * 1024 + t];
    // folded BN constants: out = gelu(p*cs + co)
    float c0s = vg0[j] * BN_SCALE, c0o = vb0[j] * c0s + vbe0[j];
    float c1s = vg1[j] * BN_SCALE, c1o = vb1[j] * c1s + vbe1[j];
    float c2s = vg2[j] * BN_SCALE, c2o = vb2[j] * c2s + vbe2[j];
    float zf = zbuf[b * H + h];
    // output dword/half for the MLP writer role (pair layout with stride 36)
    int ipw = j >> 1;
    int ydw = (ipw >> 5) * 36 + (ipw & 31);
    int yhalf = 2 * ydw + (j & 1);
    // y-read base for L3 role
    int ybase = (g >> 1) * 36 + (g & 1) * 16;
    // prologue: stage A for local step 0
    {
        const uint4* Ag = (const uint4*)(Ach + (size_t)b * ADW);
        uint4 a0 = Ag[t], a1 = Ag[1024 + t];
        uint4* Ad = (uint4*)ABUF[0];
        Ad[t] = a0; Ad[1024 + t] = a1;
    }
    if (t < 128) ((_Float16*)zzPd)[h] = (_Float16)zf;
    __syncthreads();

    for (int sl = 0; sl < CH; ++sl) {
        int s = s0 + sl;
        float hstep = dtb[s];
        float bd3 = bd3g[(size_t)(s * B + b) * H + h];
        // prefetch next step's A into registers
        uint4 p0, p1;
        {
            int sn = (sl + 1 < CH) ? sl + 1 : sl;
            const uint4* Ag = (const uint4*)(Ach + (size_t)(sn * B + b) * ADW);
            p0 = Ag[t]; p1 = Ag[1024 + t];
        }
        const uint32_t* AL = ABUF[sl & 1];
        float ksum = 0.f, kcur = 0.f;
        for (int r = 0; r < 4; ++r) {
            // ---- L0: 128 -> 256, quarter-K ----
            {
                float p = 0.f;
                const uint4* zq = (const uint4*)(zzPd + q * 16);
#pragma unroll
                for (int u4 = 0; u4 < 4; ++u4) {
                    uint4 zv = zq[u4];
                    p = fdot2u(w0h[4*u4+0], zv.x, p); p = fdot2u(w0h[4*u4+1], zv.y, p);
                    p = fdot2u(w0h[4*u4+2], zv.z, p); p = fdot2u(w0h[4*u4+3], zv.w, p);
                }
                p += __shfl_xor(p, 1, 64);
                p += __shfl_xor(p, 2, 64);
                if (q == 0) ((_Float16*)yA)[yhalf] = (_Float16)gelu_fast(p * c0s + c0o);
            }
            __syncthreads();
            // ---- L1: 256 -> 256 ----
            {
                float p = 0.f;
                const uint4* yq = (const uint4*)(yA + q * 36);
#pragma unroll
                for (int u4 = 0; u4 < 8; ++u4) {
                    uint4 yv = yq[u4];
                    p = fdot2u(w1h[4*u4+0], yv.x, p); p = fdot2u(w1h[4*u4+1], yv.y, p);
                    p = fdot2u(w1h[4*u4+2], yv.z, p); p = fdot2u(w1h[4*u4+3], yv.w, p);
                }
                p += __shfl_xor(p, 1, 64);
                p += __shfl_xor(p, 2, 64);
                if (q == 0) ((_Float16*)yB)[yhalf] = (_Float16)gelu_fast(p * c1s + c1o);
            }
            __syncthreads();
            // ---- L2: 256 -> 256 ----
            {
                float p = 0.f;
                const uint4* yq = (const uint4*)(yB + q * 36);
#pragma unroll
                for (int u4 = 0; u4 < 8; ++u4) {
                    uint4 yv = yq[u4];
                    p = fdot2u(w2h[4*u4+0], yv.x, p); p = fdot2u(w2h[4*u4+1], yv.y, p);
                    p = fdot2u(w2h[4*u4+2], yv.z, p); p = fdot2u(w2h[4*u4+3], yv.w, p);
                }
                p += __shfl_xor(p, 1, 64);
                p += __shfl_xor(p, 2, 64);
                if (q == 0) ((_Float16*)yC)[yhalf] = (_Float16)gelu_fast(p * c2s + c2o);
            }
            __syncthreads();
            // ---- L3 partials: lane (h,g) covers k-quads g*8..g*8+7 ----
            {
                float p = 0.f, p2 = 0.f;
                const uint4* yq = (const uint4*)(yC + ybase);
#pragma unroll
                for (int u4 = 0; u4 < 4; ++u4) {
                    uint4 yv = yq[u4];
                    int k0 = g * 8 + 2 * u4;
                    uint32_t Qa = AL[k0 * 128 + h];
                    uint32_t Qb = AL[(k0 + 1) * 128 + h];
                    p  = fdot2u(__builtin_amdgcn_perm(0u, Qa, 0x010C000Cu), yv.x, p);
                    p2 = fdot2u(__builtin_amdgcn_perm(0u, Qa, 0x030C020Cu), yv.y, p2);
                    p  = fdot2u(__builtin_amdgcn_perm(0u, Qb, 0x010C000Cu), yv.z, p);
                    p2 = fdot2u(__builtin_amdgcn_perm(0u, Qb, 0x030C020Cu), yv.w, p2);
                }
                psum[g][h] = p + p2;
            }
            __syncthreads();
            // ---- state update (t < 128) ----
            if (t < 128) {
                float acc = bd3;
#pragma unroll
                for (int gg = 0; gg < 8; ++gg) acc += psum[gg][h];
                kcur = acc;
                float wsm = (r == 1 || r == 2) ? 2.f : 1.f;
                ksum += wsm * kcur;
                float zz;
                if (r < 3) {
                    float cin = (r == 2) ? 1.f : 0.5f;
                    zz = zf + cin * hstep * kcur;
                } else {
                    zf += hstep * (1.f / 6.f) * ksum;
                    zz = zf;
                }
                ((_Float16*)zzPd)[h] = (_Float16)zz;
            }
            if (r == 3) {  // stage prefetched A into the other buffer
                uint4* Ad = (uint4*)ABUF[(sl + 1) & 1];
                Ad[t] = p0; Ad[1024 + t] = p1;
            }
            __syncthreads();
        }
    }
    if (t < 128) zbuf[b * H + h] = zf;
}

// ---------------------------------------------------------------------------
// attended = (zT@wv+bv)@wo+bo.  One block per sample, 128 threads.
// ---------------------------------------------------------------------------
__global__ void att_kernel(const float* __restrict__ zbuf,
                           const float* __restrict__ wv, const float* __restrict__ bv,
                           const float* __restrict__ wo, const float* __restrict__ bo,
                           float* __restrict__ att) {
    __shared__ float zl[H], v[H];
    int b = blockIdx.x, tid = threadIdx.x;
    zl[tid] = zbuf[b * H + tid];
    __syncthreads();
    {
        float acc = bv[tid];
#pragma unroll 8
        for (int i = 0; i < H; ++i) acc += zl[i] * wv[i * H + tid];
        v[tid] = acc;
    }
    __syncthreads();
    {
        float acc = bo[tid];
#pragma unroll 8
        for (int i = 0; i < H; ++i) acc += v[i] * wo[i * H + tid];
        att[b * H + tid] = acc;
    }
}

// ---------------------------------------------------------------------------
// Decoder: one single-wave block per (t, b).  grid = T*B = 5120.
// ---------------------------------------------------------------------------
__global__ void __launch_bounds__(64) dec_kernel(
    const float* __restrict__ att,
    const float* __restrict__ dw1, const float* __restrict__ db1,
    const float* __restrict__ dw2, const float* __restrict__ db2,
    const float* __restrict__ dw3, const float* __restrict__ db3,
    float* __restrict__ out) {
    int bid = blockIdx.x;
    int t = bid >> 8, b = bid & 255;
    int tid = threadIdx.x;
    __shared__ float al[H], h1l[64];
    al[tid] = att[b * H + tid];
    al[tid + 64] = att[b * H + tid + 64];
    __syncthreads();
    {
        float acc = db1[t * 64 + tid];
#pragma unroll 8
        for (int i = 0; i < H; ++i) acc += al[i] * dw1[t * H * 64 + i * 64 + tid];
        h1l[tid] = gelu_exact(acc);
    }
    __syncthreads();
    float v = 0.f;
    if (tid < 32) {
        float acc = db2[t * 32 + tid];
#pragma unroll 8
        for (int i = 0; i < 64; ++i) acc += h1l[i] * dw2[t * 64 * 32 + i * 32 + tid];
        v = gelu_exact(acc) * dw3[t * 32 + tid];
    }
#pragma unroll
    for (int off = 16; off >= 1; off >>= 1) v += __shfl_down(v, off, 64);
    if (tid == 0) out[b * T + t] = 1.f / (1.f + expf(-(v + db3[t])));
}

// ---------------------------------------------------------------------------
extern "C" void kernel_launch(void* const* d_in, const int* in_sizes, int n_in,
                              void* d_out, int out_size, void* d_ws, size_t ws_size,
                              hipStream_t stream) {
    const float* path = (const float*)d_in[0];
    const float* ts   = (const float*)d_in[1];
    const float* ew1  = (const float*)d_in[2];
    const float* eb1  = (const float*)d_in[3];
    const float* eg1  = (const float*)d_in[4];
    const float* ebe1 = (const float*)d_in[5];
    const float* ew2  = (const float*)d_in[6];
    const float* eb2  = (const float*)d_in[7];
    const float* eg2  = (const float*)d_in[8];
    const float* ebe2 = (const float*)d_in[9];
    const float* vw0  = (const float*)d_in[10];
    const float* vb0  = (const float*)d_in[11];
    const float* vg0  = (const float*)d_in[12];
    const float* vbe0 = (const float*)d_in[13];
    const float* vw1  = (const float*)d_in[14];
    const float* vb1  = (const float*)d_in[15];
    const float* vg1  = (const float*)d_in[16];
    const float* vbe1 = (const float*)d_in[17];
    const float* vw2  = (const float*)d_in[18];
    const float* vb2  = (const float*)d_in[19];
    const float* vg2  = (const float*)d_in[20];
    const float* vbe2 = (const float*)d_in[21];
    const float* vw3  = (const float*)d_in[22];
    const float* vb3  = (const float*)d_in[23];
    const float* wv   = (const float*)d_in[24];
    const float* bv   = (const float*)d_in[25];
    const float* wo   = (const float*)d_in[26];
    const float* bo   = (const float*)d_in[27];
    const float* dw1  = (const float*)d_in[28];
    const float* db1  = (const float*)d_in[29];
    const float* dw2  = (const float*)d_in[30];
    const float* db2  = (const float*)d_in[31];
    const float* dw3  = (const float*)d_in[32];
    const float* db3  = (const float*)d_in[33];

    char* ws = (char*)d_ws;
    size_t off = 0;
    auto take = [&](size_t bytes) { char* p = ws + off; off += (bytes + 255) & ~(size_t)255; return p; };
    uint32_t* Ach   = (uint32_t*)take((size_t)CH * B * ADW * 4);    // 128 MiB
    uint32_t* dxdtp = (uint32_t*)take((size_t)NSTEP * B * DP * 4);  // 688 KB
    float*    bd3g  = (float*)take((size_t)NSTEP * B * H * 4);      // 4 MiB
    float*    dtb   = (float*)take(NSTEP * 4);
    float*    zbuf  = (float*)take((size_t)B * H * 4);
    float*    att   = (float*)take((size_t)B * H * 4);
    uint32_t* wcolQ = (uint32_t*)take((size_t)80 * 1024 * 4);       // 320 KB
    uint32_t* wq    = (uint32_t*)take((size_t)8192 * 84 * 4);       // 2.75 MB

    pack_kernel<<<(8192 * 84 + 255) / 256, 256, 0, stream>>>(vw0, vw1, vw2, vw3, wcolQ, wq);
    prep_kernel<<<B, 128, 0, stream>>>(path, ts, ew1, eb1, eg1, ebe1,
                                       ew2, eb2, eg2, ebe2, vb3, zbuf, dxdtp, bd3g, dtb);
    for (int c = 0; c < NSTEP / CH; ++c) {
        aphase_kernel<<<2048, 256, 0, stream>>>(wq, dxdtp, Ach, c * CH);
        scan_kernel<<<B, 1024, 0, stream>>>(wcolQ, Ach,
                                            vb0, vg0, vbe0, vb1, vg1, vbe1, vb2, vg2, vbe2,
                                            bd3g, dtb, zbuf, c * CH);
    }
    att_kernel<<<B, 128, 0, stream>>>(zbuf, wv, bv, wo, bo, att);
    dec_kernel<<<T * B, 64, 0, stream>>>(att, dw1, db1, dw2, db2, dw3, db3, (float*)d_out);
}

// Round 9
// 662.586 us; speedup vs baseline: 1.1588x; 1.1588x over previous
//
#include <hip/hip_runtime.h>
#include <cstdint>

constexpr int B    = 256;
constexpr int S    = 33;
constexpr int D    = 42;
constexpr int H    = 128;
constexpr int HFF  = 256;
constexpr int T    = 20;
constexpr int NSTEP = S - 1;   // 32
constexpr int DP   = D / 2;    // 21 f16 d-pairs
constexpr int ADW  = 8192;     // dwords per (s,b) A-slice (e5m2, 32 KB)
constexpr int CH   = 16;       // steps per chunk (A chunk = 128 MiB)
#define BN_SCALE 0.9999950000374997f

typedef _Float16 h2v __attribute__((ext_vector_type(2)));
union UH2 { uint32_t u; h2v h; };

__device__ __forceinline__ float fdot2u(uint32_t a, uint32_t b, float c) {
    UH2 x, y; x.u = a; y.u = b;
    return __builtin_amdgcn_fdot2(x.h, y.h, c, false);
}
__device__ __forceinline__ uint32_t packh2(float a, float b) {
    UH2 u; u.h = h2v{(_Float16)a, (_Float16)b}; return u.u;
}
__device__ __forceinline__ float gelu_exact(float x) {
    return 0.5f * x * (1.0f + erff(x * 0.70710678118654752f));
}
// fast gelu for the hot scan (err ~3e-4, far under the 1e-2 threshold)
__device__ __forceinline__ float gelu_fast(float x) {
    float inner = x * (1.0f + 0.044715f * x * x);
    float E = __expf(1.5957691216f * inner);
    return x * E * __frcp_rn(E + 1.0f);
}

// ---------------------------------------------------------------------------
// Pack (one-time):
//  wcol[r*512 + t]: f16-pair weight-column slices for the 512-thread scan.
//    t -> (j = t>>1, half = t&1).  r<32: w0 ip=half*32+r; r in [32,96): w1
//    ip=half*64+(r-32); r in [96,160): w2 ip=half*64+(r-96).
//    pair = (w[2ip][j], w[2ip+1][j]).
//  wq[u*84 + row*21 + dp], u = k*128+h (k = e-quad): row e = 4k+row of w3.
//  (aphase reads it as hu*42 contiguous: half-unit hu=2u+half2 covers rows
//   {2*half2, 2*half2+1}.)
// ---------------------------------------------------------------------------
__global__ void pack_kernel(const float* __restrict__ w0, const float* __restrict__ w1,
                            const float* __restrict__ w2, const float* __restrict__ w3,
                            uint32_t* __restrict__ wcol, uint32_t* __restrict__ wq) {
    int idx = blockIdx.x * 256 + threadIdx.x;
    if (idx < 160 * 512) {
        int r = idx >> 9, t = idx & 511;
        int j = t >> 1, half = t & 1;
        float a, bb;
        if (r < 32)      { int ip = half * 32 + r;      a = w0[(2*ip)*HFF + j]; bb = w0[(2*ip+1)*HFF + j]; }
        else if (r < 96) { int ip = half * 64 + (r-32); a = w1[(2*ip)*HFF + j]; bb = w1[(2*ip+1)*HFF + j]; }
        else             { int ip = half * 64 + (r-96); a = w2[(2*ip)*HFF + j]; bb = w2[(2*ip+1)*HFF + j]; }
        wcol[idx] = packh2(a, bb);
    }
    if (idx < 8192 * 84) {
        int u = idx / 84, r = idx % 84;
        int k = u >> 7, h = u & 127;
        int row = r / 21, dp = r % 21;
        int e = 4 * k + row;
        wq[idx] = packh2(w3[e * (H * D) + h * D + 2 * dp],
                         w3[e * (H * D) + h * D + 2 * dp + 1]);
    }
}

// ---------------------------------------------------------------------------
// Prep: encoder z0, dxdt f16 pairs, bd3g[s,b,h], dt.  1 block/sample.
// ---------------------------------------------------------------------------
__global__ void prep_kernel(const float* __restrict__ path, const float* __restrict__ ts,
                            const float* __restrict__ ew1, const float* __restrict__ eb1,
                            const float* __restrict__ eg1, const float* __restrict__ ebe1,
                            const float* __restrict__ ew2, const float* __restrict__ eb2,
                            const float* __restrict__ eg2, const float* __restrict__ ebe2,
                            const float* __restrict__ b3,
                            float* __restrict__ zbuf, uint32_t* __restrict__ dxdtp,
                            float* __restrict__ bd3g, float* __restrict__ dtb) {
    __shared__ float x0[D], hb[H], dxs[NSTEP][D];
    int b = blockIdx.x, tid = threadIdx.x;
    if (tid < D) x0[tid] = path[b * S * D + tid];
    __syncthreads();
    {
        float acc = eb1[tid];
        for (int d = 0; d < D; ++d) acc += x0[d] * ew1[d * H + tid];
        hb[tid] = gelu_exact(acc * (eg1[tid] * BN_SCALE) + ebe1[tid]);
    }
    __syncthreads();
    {
        float acc = eb2[tid];
        for (int i = 0; i < H; ++i) acc += hb[i] * ew2[i * H + tid];
        zbuf[b * H + tid] = acc * (eg2[tid] * BN_SCALE) + ebe2[tid];
    }
    for (int idx = tid; idx < NSTEP * DP; idx += 128) {
        int s = idx / DP, jj = idx % DP;
        float dtv = ts[s + 1] - ts[s];
        int base = b * S * D + s * D + 2 * jj;
        float v0 = (path[base + D] - path[base]) / dtv;
        float v1 = (path[base + D + 1] - path[base + 1]) / dtv;
        dxs[s][2 * jj] = v0; dxs[s][2 * jj + 1] = v1;
        dxdtp[(s * B + b) * DP + jj] = packh2(v0, v1);
    }
    __syncthreads();
    for (int s = 0; s < NSTEP; ++s) {
        float a = 0.f;
        for (int d = 0; d < D; ++d) a += b3[tid * D + d] * dxs[s][d];
        bd3g[(size_t)(s * B + b) * H + tid] = a;
    }
    if (b == 0 && tid < NSTEP) dtb[tid] = ts[tid + 1] - ts[tid];
}

// ---------------------------------------------------------------------------
// A-phase (per 16-step chunk), despilled: thread = half-unit hu (2 e-rows,
// wr[42] ~ 85 VGPR total incl. dx regs -> no scratch at any occupancy).
// grid = 2048 (64 hu-blocks x 32 sample-step chunks of 128).
// Output: e5m2 byte pair -> coalesced 2-byte store at halfword index hu.
// ---------------------------------------------------------------------------
__global__ void __launch_bounds__(256) aphase_kernel(
    const uint32_t* __restrict__ wq, const uint32_t* __restrict__ dxdtp,
    uint32_t* __restrict__ Ach, int s0) {
    __shared__ uint32_t dxs[128][24];                  // 12 KB (rows 16B-aligned)
    int t = threadIdx.x;
    int ub = blockIdx.x & 63, sbc = blockIdx.x >> 6;   // 64 ub x 32 sbc
    int hu = ub * 256 + t;
    uint32_t wr[42];
    const uint32_t* wp = wq + (size_t)hu * 42;
#pragma unroll
    for (int r = 0; r < 42; ++r) wr[r] = wp[r];
    for (int idx = t; idx < 128 * DP; idx += 256) {
        int i = idx / DP, j2 = idx % DP;
        int sbl = sbc * 128 + i;
        int s = s0 + (sbl >> 8), b = sbl & 255;
        dxs[i][j2] = dxdtp[(size_t)(s * B + b) * DP + j2];
    }
    __syncthreads();
    unsigned short* As = (unsigned short*)Ach;
    for (int i = 0; i < 128; ++i) {
        int sbl = sbc * 128 + i;
        uint32_t dxr[21];
        {
            const uint32_t* row = dxs[i];
            *(uint4*)&dxr[0]  = *(const uint4*)&row[0];
            *(uint4*)&dxr[4]  = *(const uint4*)&row[4];
            *(uint4*)&dxr[8]  = *(const uint4*)&row[8];
            *(uint4*)&dxr[12] = *(const uint4*)&row[12];
            *(uint4*)&dxr[16] = *(const uint4*)&row[16];
            dxr[20] = row[20];
        }
        float a0 = 0.f, a1 = 0.f;
#pragma unroll
        for (int j = 0; j < 21; ++j) {
            a0 = fdot2u(wr[j],      dxr[j], a0);
            a1 = fdot2u(wr[21 + j], dxr[j], a1);
        }
        // f16 pair -> 2 e5m2 bytes (round via +0x80, take high bytes)
        uint32_t P = packh2(a0, a1) + 0x00800080u;
        uint32_t Q = __builtin_amdgcn_perm(0u, P, 0x0C0C0301u);
        As[(size_t)sbl * (2 * ADW) + hu] = (unsigned short)Q;
    }
}

// ---------------------------------------------------------------------------
// Scan (per 16-step chunk): persistent, 1 block = 1 sample, 512 threads
// (2 blocks/CU).  R7 structure + conflict-free LDS: padded z (stride 36) and
// y (stride 68) so half-lanes hit disjoint bank sets, and all f16 LDS writes
// pair-packed into full-dword writes via shfl (no sub-dword serialization).
// ---------------------------------------------------------------------------
__global__ void __launch_bounds__(512, 1) scan_kernel(
    const uint32_t* __restrict__ wcol, const uint32_t* __restrict__ Ach,
    const float* __restrict__ vb0, const float* __restrict__ vg0, const float* __restrict__ vbe0,
    const float* __restrict__ vb1, const float* __restrict__ vg1, const float* __restrict__ vbe1,
    const float* __restrict__ vb2, const float* __restrict__ vg2, const float* __restrict__ vbe2,
    const float* __restrict__ bd3g, const float* __restrict__ dtb,
    float* __restrict__ zbuf, int s0) {
    __shared__ uint32_t ABUF[2][ADW];                 // 64 KB
    __shared__ uint32_t zzPd[72];                     // padded: half*36 + r
    __shared__ uint32_t yA[136], yB[136], yC[136];    // padded: half*68 + r
    __shared__ float psum[4][128];
    int t = threadIdx.x, b = blockIdx.x;
    int j = t >> 1, half = t & 1;                     // MLP role
    int h = t & 127, g = t >> 7;                      // L3/state role
    uint32_t w0h[32], w1h[64], w2h[64];
#pragma unroll
    for (int r = 0; r < 32; ++r) w0h[r] = wcol[r * 512 + t];
#pragma unroll
    for (int r = 0; r < 64; ++r) w1h[r] = wcol[(32 + r) * 512 + t];
#pragma unroll
    for (int r = 0; r < 64; ++r) w2h[r] = wcol[(96 + r) * 512 + t];
    // folded BN: out = gelu(p*cs + co)
    float c0s = vg0[j] * BN_SCALE, c0o = vb0[j] * c0s + vbe0[j];
    float c1s = vg1[j] * BN_SCALE, c1o = vb1[j] * c1s + vbe1[j];
    float c2s = vg2[j] * BN_SCALE, c2o = vb2[j] * c2s + vbe2[j];
    float zf = zbuf[b * H + h];
    // prologue: stage A for local step 0
    {
        const uint4* Ag = (const uint4*)(Ach + (size_t)b * ADW);
        uint4 a0 = Ag[t], a1 = Ag[512 + t], a2 = Ag[1024 + t], a3 = Ag[1536 + t];
        uint4* Ad = (uint4*)ABUF[0];
        Ad[t] = a0; Ad[512 + t] = a1; Ad[1024 + t] = a2; Ad[1536 + t] = a3;
    }
    if (t < 128) {
        float zhi = __shfl_down(zf, 1, 64);
        if ((t & 1) == 0) {
            int ip = t >> 1;
            zzPd[(ip >> 5) * 36 + (ip & 31)] = packh2(zf, zhi);
        }
    }
    __syncthreads();

    for (int sl = 0; sl < CH; ++sl) {
        int s = s0 + sl;
        float hstep = dtb[s];
        float bd3 = bd3g[(size_t)(s * B + b) * H + h];
        // prefetch next step's A into registers (in flight across the step)
        uint4 p0, p1, p2, p3;
        {
            int sn = (sl + 1 < CH) ? sl + 1 : sl;
            const uint4* Ag = (const uint4*)(Ach + (size_t)(sn * B + b) * ADW);
            p0 = Ag[t]; p1 = Ag[512 + t]; p2 = Ag[1024 + t]; p3 = Ag[1536 + t];
        }
        const uint32_t* AL = ABUF[sl & 1];
        float ksum = 0.f, kcur = 0.f;
        for (int r = 0; r < 4; ++r) {
            // ---- L0: 128 -> 256 (half-K per lane) ----
            {
                float p = 0.f;
                const uint4* zq = (const uint4*)(zzPd + half * 36);
#pragma unroll
                for (int u4 = 0; u4 < 8; ++u4) {
                    uint4 zv = zq[u4];
                    p = fdot2u(w0h[4*u4+0], zv.x, p); p = fdot2u(w0h[4*u4+1], zv.y, p);
                    p = fdot2u(w0h[4*u4+2], zv.z, p); p = fdot2u(w0h[4*u4+3], zv.w, p);
                }
                p += __shfl_xor(p, 1, 64);
                float v = gelu_fast(p * c0s + c0o);
                float vhi = __shfl_down(v, 2, 64);
                if ((t & 3) == 0) {
                    int ip = t >> 2;
                    yA[(ip >> 6) * 68 + (ip & 63)] = packh2(v, vhi);
                }
            }
            __syncthreads();
            // ---- L1: 256 -> 256 ----
            {
                float p = 0.f;
                const uint4* yq = (const uint4*)(yA + half * 68);
#pragma unroll
                for (int u4 = 0; u4 < 16; ++u4) {
                    uint4 yv = yq[u4];
                    p = fdot2u(w1h[4*u4+0], yv.x, p); p = fdot2u(w1h[4*u4+1], yv.y, p);
                    p = fdot2u(w1h[4*u4+2], yv.z, p); p = fdot2u(w1h[4*u4+3], yv.w, p);
                }
                p += __shfl_xor(p, 1, 64);
                float v = gelu_fast(p * c1s + c1o);
                float vhi = __shfl_down(v, 2, 64);
                if ((t & 3) == 0) {
                    int ip = t >> 2;
                    yB[(ip >> 6) * 68 + (ip & 63)] = packh2(v, vhi);
                }
            }
            __syncthreads();
            // ---- L2: 256 -> 256 ----
            {
                float p = 0.f;
                const uint4* yq = (const uint4*)(yB + half * 68);
#pragma unroll
                for (int u4 = 0; u4 < 16; ++u4) {
                    uint4 yv = yq[u4];
                    p = fdot2u(w2h[4*u4+0], yv.x, p); p = fdot2u(w2h[4*u4+1], yv.y, p);
                    p = fdot2u(w2h[4*u4+2], yv.z, p); p = fdot2u(w2h[4*u4+3], yv.w, p);
                }
                p += __shfl_xor(p, 1, 64);
                float v = gelu_fast(p * c2s + c2o);
                float vhi = __shfl_down(v, 2, 64);
                if ((t & 3) == 0) {
                    int ip = t >> 2;
                    yC[(ip >> 6) * 68 + (ip & 63)] = packh2(v, vhi);
                }
            }
            __syncthreads();
            // ---- L3 partials: lane (h,g) covers k-quads g*16..g*16+15 ----
            {
                float p = 0.f, p2 = 0.f;
                int ybase = (g >> 1) * 68 + (g & 1) * 32;
                const uint4* yq = (const uint4*)(yC + ybase);
#pragma unroll
                for (int kk = 0; kk < 8; ++kk) {
                    uint4 yv = yq[kk];
                    int k0 = g * 16 + 2 * kk;
                    uint32_t Qa = AL[k0 * 128 + h];
                    uint32_t Qb = AL[(k0 + 1) * 128 + h];
                    p  = fdot2u(__builtin_amdgcn_perm(0u, Qa, 0x010C000Cu), yv.x, p);
                    p2 = fdot2u(__builtin_amdgcn_perm(0u, Qa, 0x030C020Cu), yv.y, p2);
                    p  = fdot2u(__builtin_amdgcn_perm(0u, Qb, 0x010C000Cu), yv.z, p);
                    p2 = fdot2u(__builtin_amdgcn_perm(0u, Qb, 0x030C020Cu), yv.w, p2);
                }
                psum[g][h] = p + p2;
            }
            __syncthreads();
            // ---- state update (t < 128), pair-packed zz write ----
            if (t < 128) {
                kcur = bd3 + psum[0][h] + psum[1][h] + psum[2][h] + psum[3][h];
                float wsm = (r == 1 || r == 2) ? 2.f : 1.f;
                ksum += wsm * kcur;
                float zz;
                if (r < 3) {
                    float cin = (r == 2) ? 1.f : 0.5f;
                    zz = zf + cin * hstep * kcur;
                } else {
                    zf += hstep * (1.f / 6.f) * ksum;
                    zz = zf;
                }
                float zhi = __shfl_down(zz, 1, 64);
                if ((t & 1) == 0) {
                    int ip = t >> 1;
                    zzPd[(ip >> 5) * 36 + (ip & 31)] = packh2(zz, zhi);
                }
            }
            if (r == 3) {  // stage prefetched A into the other buffer
                uint4* Ad = (uint4*)ABUF[(sl + 1) & 1];
                Ad[t] = p0; Ad[512 + t] = p1; Ad[1024 + t] = p2; Ad[1536 + t] = p3;
            }
            __syncthreads();
        }
    }
    if (t < 128) zbuf[b * H + h] = zf;
}

// ---------------------------------------------------------------------------
// attended = (zT@wv+bv)@wo+bo.  One block per sample, 128 threads.
// ---------------------------------------------------------------------------
__global__ void att_kernel(const float* __restrict__ zbuf,
                           const float* __restrict__ wv, const float* __restrict__ bv,
                           const float* __restrict__ wo, const float* __restrict__ bo,
                           float* __restrict__ att) {
    __shared__ float zl[H], v[H];
    int b = blockIdx.x, tid = threadIdx.x;
    zl[tid] = zbuf[b * H + tid];
    __syncthreads();
    {
        float acc = bv[tid];
#pragma unroll 8
        for (int i = 0; i < H; ++i) acc += zl[i] * wv[i * H + tid];
        v[tid] = acc;
    }
    __syncthreads();
    {
        float acc = bo[tid];
#pragma unroll 8
        for (int i = 0; i < H; ++i) acc += v[i] * wo[i * H + tid];
        att[b * H + tid] = acc;
    }
}

// ---------------------------------------------------------------------------
// Decoder: one single-wave block per (t, b).  grid = T*B = 5120.
// ---------------------------------------------------------------------------
__global__ void __launch_bounds__(64) dec_kernel(
    const float* __restrict__ att,
    const float* __restrict__ dw1, const float* __restrict__ db1,
    const float* __restrict__ dw2, const float* __restrict__ db2,
    const float* __restrict__ dw3, const float* __restrict__ db3,
    float* __restrict__ out) {
    int bid = blockIdx.x;
    int t = bid >> 8, b = bid & 255;
    int tid = threadIdx.x;
    __shared__ float al[H], h1l[64];
    al[tid] = att[b * H + tid];
    al[tid + 64] = att[b * H + tid + 64];
    __syncthreads();
    {
        float acc = db1[t * 64 + tid];
#pragma unroll 8
        for (int i = 0; i < H; ++i) acc += al[i] * dw1[t * H * 64 + i * 64 + tid];
        h1l[tid] = gelu_exact(acc);
    }
    __syncthreads();
    float v = 0.f;
    if (tid < 32) {
        float acc = db2[t * 32 + tid];
#pragma unroll 8
        for (int i = 0; i < 64; ++i) acc += h1l[i] * dw2[t * 64 * 32 + i * 32 + tid];
        v = gelu_exact(acc) * dw3[t * 32 + tid];
    }
#pragma unroll
    for (int off = 16; off >= 1; off >>= 1) v += __shfl_down(v, off, 64);
    if (tid == 0) out[b * T + t] = 1.f / (1.f + expf(-(v + db3[t])));
}

// ---------------------------------------------------------------------------
extern "C" void kernel_launch(void* const* d_in, const int* in_sizes, int n_in,
                              void* d_out, int out_size, void* d_ws, size_t ws_size,
                              hipStream_t stream) {
    const float* path = (const float*)d_in[0];
    const float* ts   = (const float*)d_in[1];
    const float* ew1  = (const float*)d_in[2];
    const float* eb1  = (const float*)d_in[3];
    const float* eg1  = (const float*)d_in[4];
    const float* ebe1 = (const float*)d_in[5];
    const float* ew2  = (const float*)d_in[6];
    const float* eb2  = (const float*)d_in[7];
    const float* eg2  = (const float*)d_in[8];
    const float* ebe2 = (const float*)d_in[9];
    const float* vw0  = (const float*)d_in[10];
    const float* vb0  = (const float*)d_in[11];
    const float* vg0  = (const float*)d_in[12];
    const float* vbe0 = (const float*)d_in[13];
    const float* vw1  = (const float*)d_in[14];
    const float* vb1  = (const float*)d_in[15];
    const float* vg1  = (const float*)d_in[16];
    const float* vbe1 = (const float*)d_in[17];
    const float* vw2  = (const float*)d_in[18];
    const float* vb2  = (const float*)d_in[19];
    const float* vg2  = (const float*)d_in[20];
    const float* vbe2 = (const float*)d_in[21];
    const float* vw3  = (const float*)d_in[22];
    const float* vb3  = (const float*)d_in[23];
    const float* wv   = (const float*)d_in[24];
    const float* bv   = (const float*)d_in[25];
    const float* wo   = (const float*)d_in[26];
    const float* bo   = (const float*)d_in[27];
    const float* dw1  = (const float*)d_in[28];
    const float* db1  = (const float*)d_in[29];
    const float* dw2  = (const float*)d_in[30];
    const float* db2  = (const float*)d_in[31];
    const float* dw3  = (const float*)d_in[32];
    const float* db3  = (const float*)d_in[33];

    char* ws = (char*)d_ws;
    size_t off = 0;
    auto take = [&](size_t bytes) { char* p = ws + off; off += (bytes + 255) & ~(size_t)255; return p; };
    uint32_t* Ach   = (uint32_t*)take((size_t)CH * B * ADW * 4);    // 128 MiB
    uint32_t* dxdtp = (uint32_t*)take((size_t)NSTEP * B * DP * 4);  // 688 KB
    float*    bd3g  = (float*)take((size_t)NSTEP * B * H * 4);      // 4 MiB
    float*    dtb   = (float*)take(NSTEP * 4);
    float*    zbuf  = (float*)take((size_t)B * H * 4);
    float*    att   = (float*)take((size_t)B * H * 4);
    uint32_t* wcol  = (uint32_t*)take((size_t)160 * 512 * 4);       // 320 KB
    uint32_t* wq    = (uint32_t*)take((size_t)8192 * 84 * 4);       // 2.75 MB

    pack_kernel<<<(8192 * 84 + 255) / 256, 256, 0, stream>>>(vw0, vw1, vw2, vw3, wcol, wq);
    prep_kernel<<<B, 128, 0, stream>>>(path, ts, ew1, eb1, eg1, ebe1,
                                       ew2, eb2, eg2, ebe2, vb3, zbuf, dxdtp, bd3g, dtb);
    for (int c = 0; c < NSTEP / CH; ++c) {
        aphase_kernel<<<2048, 256, 0, stream>>>(wq, dxdtp, Ach, c * CH);
        scan_kernel<<<B, 512, 0, stream>>>(wcol, Ach,
                                           vb0, vg0, vbe0, vb1, vg1, vbe1, vb2, vg2, vbe2,
                                           bd3g, dtb, zbuf, c * CH);
    }
    att_kernel<<<B, 128, 0, stream>>>(zbuf, wv, bv, wo, bo, att);
    dec_kernel<<<T * B, 64, 0, stream>>>(att, dw1, db1, dw2, db2, dw3, db3, (float*)d_out);
}